// Round 1
// baseline (2682.357 us; speedup 1.0000x reference)
//
#include <hip/hip_runtime.h>
#include <math.h>

// Problem constants (fixed by reference)
#define SS 2048
#define EE 768
#define HH 12
#define DHH 64
#define FFF 3072
#define LL 4

// ---------------------------------------------------------------------------
// x = inputs_embeds + wpe   (elementwise, float4)
// ---------------------------------------------------------------------------
__global__ __launch_bounds__(256) void add_embed_kernel(
    const float* __restrict__ a, const float* __restrict__ b, float* __restrict__ out) {
  int i = (blockIdx.x * 256 + threadIdx.x) * 4;
  float4 av = *(const float4*)(a + i);
  float4 bv = *(const float4*)(b + i);
  float4 o; o.x = av.x + bv.x; o.y = av.y + bv.y; o.z = av.z + bv.z; o.w = av.w + bv.w;
  *(float4*)(out + i) = o;
}

// ---------------------------------------------------------------------------
// LayerNorm over E=768. One block (256 thr) per row; 3 elems/thread.
// ---------------------------------------------------------------------------
__global__ __launch_bounds__(256) void ln_kernel(
    const float* __restrict__ x, const float* __restrict__ g,
    const float* __restrict__ bta, float* __restrict__ out) {
  int row = blockIdx.x;
  int tid = threadIdx.x;
  const float* xr = x + row * EE;
  float v0 = xr[tid], v1 = xr[tid + 256], v2 = xr[tid + 512];
  float s  = v0 + v1 + v2;
  float s2 = v0 * v0 + v1 * v1 + v2 * v2;
  #pragma unroll
  for (int off = 32; off >= 1; off >>= 1) {
    s  += __shfl_down(s,  off);
    s2 += __shfl_down(s2, off);
  }
  __shared__ float red[8];
  __shared__ float mb[2];
  int lane = tid & 63, wid = tid >> 6;
  if (lane == 0) { red[wid] = s; red[4 + wid] = s2; }
  __syncthreads();
  if (tid == 0) {
    float ts  = red[0] + red[1] + red[2] + red[3];
    float ts2 = red[4] + red[5] + red[6] + red[7];
    float mu  = ts * (1.0f / EE);
    float var = ts2 * (1.0f / EE) - mu * mu;
    mb[0] = mu; mb[1] = rsqrtf(var + 1e-5f);
  }
  __syncthreads();
  float mu = mb[0], rs = mb[1];
  float* orow = out + row * EE;
  orow[tid]       = (v0 - mu) * rs * g[tid]       + bta[tid];
  orow[tid + 256] = (v1 - mu) * rs * g[tid + 256] + bta[tid + 256];
  orow[tid + 512] = (v2 - mu) * rs * g[tid + 512] + bta[tid + 512];
}

// ---------------------------------------------------------------------------
// Generic fp32 GEMM: C[M,N] = A[M,K] @ W[K,N] + bias, epilogue by mode:
//   mode 0: store       mode 1: exact GELU       mode 2: += res (residual)
// 64x64 block tile, BK=16, 256 threads, 4x4 micro-tile.
// Grid: (N/64, M/64). M=2048 always.
// ---------------------------------------------------------------------------
__global__ __launch_bounds__(256) void gemm64_kernel(
    const float* __restrict__ A, const float* __restrict__ W,
    const float* __restrict__ bias, const float* res, float* C,
    int K, int N, int mode) {
  // As stored transposed [k][m], +4 pad keeps rows 16B-aligned and conflict-light
  __shared__ float As[16][68];
  __shared__ float Bs[16][64];
  int tid = threadIdx.x;
  int m0 = blockIdx.y * 64, n0 = blockIdx.x * 64;
  int ar = tid >> 2, ak = (tid & 3) * 4;    // A tile load: 64 rows x 16 k
  int br = tid >> 4, bn = (tid & 15) * 4;   // B tile load: 16 k x 64 n
  int tx = tid & 15, ty = tid >> 4;         // micro-tile coords
  float acc[4][4] = {};
  const float* Aptr = A + (m0 + ar) * K + ak;
  const float* Wptr = W + br * N + n0 + bn;
  for (int k0 = 0; k0 < K; k0 += 16) {
    float4 av = *(const float4*)(Aptr + k0);
    float4 bv = *(const float4*)(Wptr + (size_t)k0 * N);
    As[ak + 0][ar] = av.x; As[ak + 1][ar] = av.y;
    As[ak + 2][ar] = av.z; As[ak + 3][ar] = av.w;
    *(float4*)&Bs[br][bn] = bv;
    __syncthreads();
    #pragma unroll
    for (int kk = 0; kk < 16; kk++) {
      float4 a4 = *(const float4*)&As[kk][ty * 4];
      float4 b4 = *(const float4*)&Bs[kk][tx * 4];
      acc[0][0] += a4.x * b4.x; acc[0][1] += a4.x * b4.y; acc[0][2] += a4.x * b4.z; acc[0][3] += a4.x * b4.w;
      acc[1][0] += a4.y * b4.x; acc[1][1] += a4.y * b4.y; acc[1][2] += a4.y * b4.z; acc[1][3] += a4.y * b4.w;
      acc[2][0] += a4.z * b4.x; acc[2][1] += a4.z * b4.y; acc[2][2] += a4.z * b4.z; acc[2][3] += a4.z * b4.w;
      acc[3][0] += a4.w * b4.x; acc[3][1] += a4.w * b4.y; acc[3][2] += a4.w * b4.z; acc[3][3] += a4.w * b4.w;
    }
    __syncthreads();
  }
  #pragma unroll
  for (int i = 0; i < 4; i++) {
    int row = m0 + ty * 4 + i;
    float* crow = C + (size_t)row * N + n0 + tx * 4;
    const float* rrow = res + (size_t)row * N + n0 + tx * 4;  // only deref'd if mode==2
    #pragma unroll
    for (int j = 0; j < 4; j++) {
      float val = acc[i][j] + bias[n0 + tx * 4 + j];
      if (mode == 1) {
        val = 0.5f * val * (1.0f + erff(val * 0.70710678118654752f));  // exact GELU
      } else if (mode == 2) {
        val += rrow[j];
      }
      crow[j] = val;
    }
  }
}

// ---------------------------------------------------------------------------
// KtV[h] = scale * K_h^T @ V_h   (64x64 per head, sum over S)
// No softmax -> attention is linear -> associativity: a = Q (scale * K^T V).
// Grid: (H, S/64). Each block handles 64 s-rows, atomically accumulates.
// ktv buffer must be zeroed first.
// ---------------------------------------------------------------------------
__global__ __launch_bounds__(256) void ktv_kernel(
    const float* __restrict__ kmat, const float* __restrict__ vmat,
    float* __restrict__ ktv) {
  int h = blockIdx.x, c = blockIdx.y;
  __shared__ float Ks[8][64];
  __shared__ float Vs[8][64];
  int tid = threadIdx.x;
  int i  = tid >> 2;            // output row (K-feature dim), 0..63
  int j0 = (tid & 3) * 16;      // 16 output cols per thread
  int rr = tid >> 4, cc = (tid & 15) * 4;  // staging coords (16 rows x 64 cols)
  float acc[16] = {};
  int sbase = c * 64;
  for (int so = 0; so < 64; so += 8) {
    const float* src = (rr < 8)
        ? (kmat + (size_t)(sbase + so + rr) * EE + h * DHH + cc)
        : (vmat + (size_t)(sbase + so + rr - 8) * EE + h * DHH + cc);
    float4 t4 = *(const float4*)src;
    if (rr < 8) { *(float4*)&Ks[rr][cc] = t4; } else { *(float4*)&Vs[rr - 8][cc] = t4; }
    __syncthreads();
    #pragma unroll
    for (int s = 0; s < 8; s++) {
      float kv = Ks[s][i];
      #pragma unroll
      for (int j = 0; j < 16; j++) acc[j] += kv * Vs[s][j0 + j];
    }
    __syncthreads();
  }
  float* dst = ktv + h * DHH * DHH + i * DHH + j0;
  #pragma unroll
  for (int j = 0; j < 16; j++) atomicAdd(dst + j, acc[j] * 0.125f);  // scale = DH^-0.5
}

// ---------------------------------------------------------------------------
// a[:, h, :] = Q_h @ KtV_h    ([2048x64] @ [64x64] per head)
// Grid: (S/32, H). KtV_h cached in LDS.
// ---------------------------------------------------------------------------
__global__ __launch_bounds__(256) void qktv_kernel(
    const float* __restrict__ q, const float* __restrict__ ktv,
    float* __restrict__ a) {
  int h = blockIdx.y, m0 = blockIdx.x * 32;
  __shared__ float Ks[64 * 64];
  __shared__ float Qs[32][65];
  int tid = threadIdx.x;
  const float* kt = ktv + h * DHH * DHH;
  #pragma unroll
  for (int it = 0; it < 4; it++) {
    int idx = it * 1024 + tid * 4;
    *(float4*)&Ks[idx] = *(const float4*)&kt[idx];
  }
  #pragma unroll
  for (int it = 0; it < 2; it++) {
    int idx = it * 1024 + tid * 4;     // 32x64 Q tile
    int r = idx >> 6, ccol = idx & 63;
    float4 t4 = *(const float4*)&q[(size_t)(m0 + r) * EE + h * DHH + ccol];
    Qs[r][ccol] = t4.x; Qs[r][ccol + 1] = t4.y; Qs[r][ccol + 2] = t4.z; Qs[r][ccol + 3] = t4.w;
  }
  __syncthreads();
  int r = tid >> 3, c0 = (tid & 7) * 8;
  float acc[8] = {};
  #pragma unroll 8
  for (int kk = 0; kk < 64; kk++) {
    float qv = Qs[r][kk];
    float4 b0 = *(const float4*)&Ks[kk * 64 + c0];
    float4 b1 = *(const float4*)&Ks[kk * 64 + c0 + 4];
    acc[0] += qv * b0.x; acc[1] += qv * b0.y; acc[2] += qv * b0.z; acc[3] += qv * b0.w;
    acc[4] += qv * b1.x; acc[5] += qv * b1.y; acc[6] += qv * b1.z; acc[7] += qv * b1.w;
  }
  float* dst = a + (size_t)(m0 + r) * EE + h * DHH + c0;
  float4 o0; o0.x = acc[0]; o0.y = acc[1]; o0.z = acc[2]; o0.w = acc[3];
  float4 o1; o1.x = acc[4]; o1.y = acc[5]; o1.z = acc[6]; o1.w = acc[7];
  *(float4*)dst = o0; *(float4*)(dst + 4) = o1;
}

// ---------------------------------------------------------------------------
extern "C" void kernel_launch(void* const* d_in, const int* in_sizes, int n_in,
                              void* d_out, int out_size, void* d_ws, size_t ws_size,
                              hipStream_t stream) {
  const float* emb  = (const float*)d_in[0];
  const float* wpe  = (const float*)d_in[1];
  const float* ln1g = (const float*)d_in[2];
  const float* ln1b = (const float*)d_in[3];
  const float* Wq   = (const float*)d_in[4];
  const float* bq   = (const float*)d_in[5];
  const float* Wk   = (const float*)d_in[6];
  const float* bk   = (const float*)d_in[7];
  const float* Wv   = (const float*)d_in[8];
  const float* bv   = (const float*)d_in[9];
  const float* Wo   = (const float*)d_in[10];
  const float* bo   = (const float*)d_in[11];
  const float* ln2g = (const float*)d_in[12];
  const float* ln2b = (const float*)d_in[13];
  const float* W1   = (const float*)d_in[14];
  const float* b1   = (const float*)d_in[15];
  const float* W2   = (const float*)d_in[16];
  const float* b2   = (const float*)d_in[17];
  const float* lnfg = (const float*)d_in[18];
  const float* lnfb = (const float*)d_in[19];

  // Workspace layout (floats). Total ~14.2M floats = ~57 MB.
  float* x   = (float*)d_ws;       // S*E  residual stream
  float* hb  = x  + SS * EE;       // S*E  LN output
  float* qb  = hb + SS * EE;       // S*E
  float* kb  = qb + SS * EE;       // S*E  (reused as attention output 'a' after ktv)
  float* vb  = kb + SS * EE;       // S*E
  float* mb2 = vb + SS * EE;       // S*FF gelu output
  float* ktv = mb2 + SS * FFF;     // H*64*64
  float* ab  = kb;                 // alias: K no longer needed once ktv built

  dim3 blk(256);
  add_embed_kernel<<<SS * EE / 1024, blk, 0, stream>>>(emb, wpe, x);
  for (int l = 0; l < LL; l++) {
    const size_t wofs = (size_t)l * EE * EE;
    ln_kernel<<<SS, blk, 0, stream>>>(x, ln1g + l * EE, ln1b + l * EE, hb);
    gemm64_kernel<<<dim3(EE / 64, SS / 64), blk, 0, stream>>>(hb, Wq + wofs, bq + l * EE, x, qb, EE, EE, 0);
    gemm64_kernel<<<dim3(EE / 64, SS / 64), blk, 0, stream>>>(hb, Wk + wofs, bk + l * EE, x, kb, EE, EE, 0);
    gemm64_kernel<<<dim3(EE / 64, SS / 64), blk, 0, stream>>>(hb, Wv + wofs, bv + l * EE, x, vb, EE, EE, 0);
    hipMemsetAsync(ktv, 0, HH * DHH * DHH * sizeof(float), stream);
    ktv_kernel<<<dim3(HH, SS / 64), blk, 0, stream>>>(kb, vb, ktv);
    qktv_kernel<<<dim3(SS / 32, HH), blk, 0, stream>>>(qb, ktv, ab);
    gemm64_kernel<<<dim3(EE / 64, SS / 64), blk, 0, stream>>>(ab, Wo + wofs, bo + l * EE, x, x, EE, EE, 2);
    ln_kernel<<<SS, blk, 0, stream>>>(x, ln2g + l * EE, ln2b + l * EE, hb);
    gemm64_kernel<<<dim3(FFF / 64, SS / 64), blk, 0, stream>>>(hb, W1 + (size_t)l * EE * FFF, b1 + l * FFF, x, mb2, EE, FFF, 1);
    gemm64_kernel<<<dim3(EE / 64, SS / 64), blk, 0, stream>>>(mb2, W2 + (size_t)l * FFF * EE, b2 + l * EE, x, x, FFF, EE, 2);
  }
  ln_kernel<<<SS, blk, 0, stream>>>(x, lnfg, lnfb, (float*)d_out);
}

// Round 2
// 1377.762 us; speedup vs baseline: 1.9469x; 1.9469x over previous
//
#include <hip/hip_runtime.h>
#include <hip/hip_bf16.h>
#include <math.h>

#define SS 2048
#define EE 768
#define HH 12
#define DHH 64
#define FFF 3072
#define LL 4

typedef __hip_bfloat16 bf16;
typedef __attribute__((ext_vector_type(8))) short short8;
typedef __attribute__((ext_vector_type(4))) float f32x4;

__device__ __forceinline__ float b2f(short u) {
  union { unsigned int i; float f; } v;
  v.i = ((unsigned int)(unsigned short)u) << 16;
  return v.f;
}
__device__ __forceinline__ bf16 f2b(float f) { return __float2bfloat16(f); }

// async global->LDS, 16B per lane. LDS dest = wave-uniform base + lane*16.
__device__ __forceinline__ void async_ld16(const void* g, void* l) {
  __builtin_amdgcn_global_load_lds(
      (const __attribute__((address_space(1))) void*)g,
      (__attribute__((address_space(3))) void*)l, 16, 0, 0);
}

// ---------------------------------------------------------------------------
// x = inputs_embeds + wpe   (fp32, float4)
// ---------------------------------------------------------------------------
__global__ __launch_bounds__(256) void add_embed_kernel(
    const float* __restrict__ a, const float* __restrict__ b, float* __restrict__ out) {
  int i = (blockIdx.x * 256 + threadIdx.x) * 4;
  float4 av = *(const float4*)(a + i);
  float4 bv = *(const float4*)(b + i);
  float4 o; o.x = av.x + bv.x; o.y = av.y + bv.y; o.z = av.z + bv.z; o.w = av.w + bv.w;
  *(float4*)(out + i) = o;
}

// ---------------------------------------------------------------------------
// LayerNorm over E=768 (fp32 in), templated output (fp32 or bf16)
// ---------------------------------------------------------------------------
template <typename OutT>
__global__ __launch_bounds__(256) void ln_kernel_t(
    const float* __restrict__ x, const float* __restrict__ g,
    const float* __restrict__ bta, OutT* __restrict__ out) {
  int row = blockIdx.x;
  int tid = threadIdx.x;
  const float* xr = x + (size_t)row * EE;
  float v0 = xr[tid], v1 = xr[tid + 256], v2 = xr[tid + 512];
  float s  = v0 + v1 + v2;
  float s2 = v0 * v0 + v1 * v1 + v2 * v2;
  #pragma unroll
  for (int off = 32; off >= 1; off >>= 1) {
    s  += __shfl_down(s,  off);
    s2 += __shfl_down(s2, off);
  }
  __shared__ float red[8];
  __shared__ float mb[2];
  int lane = tid & 63, wid = tid >> 6;
  if (lane == 0) { red[wid] = s; red[4 + wid] = s2; }
  __syncthreads();
  if (tid == 0) {
    float ts  = red[0] + red[1] + red[2] + red[3];
    float ts2 = red[4] + red[5] + red[6] + red[7];
    float mu  = ts * (1.0f / EE);
    float var = ts2 * (1.0f / EE) - mu * mu;
    mb[0] = mu; mb[1] = rsqrtf(var + 1e-5f);
  }
  __syncthreads();
  float mu = mb[0], rs = mb[1];
  OutT* orow = out + (size_t)row * EE;
  float o0 = (v0 - mu) * rs * g[tid]       + bta[tid];
  float o1 = (v1 - mu) * rs * g[tid + 256] + bta[tid + 256];
  float o2 = (v2 - mu) * rs * g[tid + 512] + bta[tid + 512];
  if constexpr (sizeof(OutT) == 4) {
    orow[tid] = o0; orow[tid + 256] = o1; orow[tid + 512] = o2;
  } else {
    orow[tid] = f2b(o0); orow[tid + 256] = f2b(o1); orow[tid + 512] = f2b(o2);
  }
}

// ---------------------------------------------------------------------------
// Tiled transpose + fp32->bf16 convert: src[K][N] f32 -> dst[N][K] bf16
// ---------------------------------------------------------------------------
__global__ __launch_bounds__(256) void transpose_bf16_kernel(
    const float* __restrict__ src, bf16* __restrict__ dst, int K, int N) {
  __shared__ float tile[32][33];
  int n0 = blockIdx.x * 32, k0 = blockIdx.y * 32;
  int tx = threadIdx.x & 31, ty = threadIdx.x >> 5;  // 32x8
  #pragma unroll
  for (int r = 0; r < 32; r += 8)
    tile[ty + r][tx] = src[(size_t)(k0 + ty + r) * N + n0 + tx];
  __syncthreads();
  #pragma unroll
  for (int r = 0; r < 32; r += 8)
    dst[(size_t)(n0 + ty + r) * K + k0 + tx] = f2b(tile[tx][ty + r]);
}

__global__ __launch_bounds__(256) void concat_bias_kernel(
    const float* __restrict__ bq, const float* __restrict__ bk,
    const float* __restrict__ bv, float* __restrict__ out) {
  int i = blockIdx.x * 256 + threadIdx.x;
  out[i] = (i < 768) ? bq[i] : (i < 1536 ? bk[i - 768] : bv[i - 1536]);
}

// ---------------------------------------------------------------------------
// bf16 MFMA GEMM (m97 structure): C[M,N] = A[M,K] @ Bt[N,K]^T + bias
// 128x128 tile, BK=32, 256 thr = 4 waves each computing 64x64 via 4x4 MFMA
// 16x16x32 tiles. global_load_lds width-16 staging, lane-linear LDS (no pad).
// mode 0: store bf16   mode 1: exact GELU -> bf16   mode 2: +res -> fp32
// ---------------------------------------------------------------------------
__global__ __launch_bounds__(256) void gemm_bf16_kernel(
    const bf16* __restrict__ A, const bf16* __restrict__ Bt,
    const float* __restrict__ bias, const float* __restrict__ res,
    void* __restrict__ Cv, int K, int N, int mode) {
  __shared__ __align__(16) short As[128 * 32];
  __shared__ __align__(16) short Bs[128 * 32];
  const int t = threadIdx.x;
  const int wave = t >> 6, lane = t & 63;
  const int m0 = blockIdx.y * 128, n0 = blockIdx.x * 128;

  // staging: thread t covers 16B chunk (row = t>>2, kchunk = t&3) + row+64
  const bf16* Ag0 = A  + (size_t)(m0 + (t >> 2)) * K + (t & 3) * 8;
  const bf16* Ag1 = A  + (size_t)(m0 + 64 + (t >> 2)) * K + (t & 3) * 8;
  const bf16* Bg0 = Bt + (size_t)(n0 + (t >> 2)) * K + (t & 3) * 8;
  const bf16* Bg1 = Bt + (size_t)(n0 + 64 + (t >> 2)) * K + (t & 3) * 8;
  short* Asw0 = As + wave * 512;         // wave-uniform LDS bases (1024 B/wave)
  short* Asw1 = As + 2048 + wave * 512;
  short* Bsw0 = Bs + wave * 512;
  short* Bsw1 = Bs + 2048 + wave * 512;

  const int fr = lane & 15, kq = lane >> 4;
  const int wm = (wave >> 1) * 64, wn = (wave & 1) * 64;
  f32x4 acc[4][4] = {};

  for (int k0 = 0; k0 < K; k0 += 32) {
    async_ld16(Ag0 + k0, Asw0);
    async_ld16(Ag1 + k0, Asw1);
    async_ld16(Bg0 + k0, Bsw0);
    async_ld16(Bg1 + k0, Bsw1);
    __syncthreads();   // drains vmcnt: LDS tiles valid
    short8 a[4], b[4];
    #pragma unroll
    for (int i = 0; i < 4; i++)
      a[i] = *(const short8*)(As + (wm + 16 * i + fr) * 32 + kq * 8);
    #pragma unroll
    for (int j = 0; j < 4; j++)
      b[j] = *(const short8*)(Bs + (wn + 16 * j + fr) * 32 + kq * 8);
    #pragma unroll
    for (int i = 0; i < 4; i++)
      #pragma unroll
      for (int j = 0; j < 4; j++)
        acc[i][j] = __builtin_amdgcn_mfma_f32_16x16x32_bf16(a[i], b[j], acc[i][j], 0, 0, 0);
    __syncthreads();   // protect LDS before next staging
  }

  // C/D layout: col = lane&15, row = (lane>>4)*4 + reg  [m89/m91-verified]
  #pragma unroll
  for (int i = 0; i < 4; i++) {
    #pragma unroll
    for (int j = 0; j < 4; j++) {
      const int r0 = m0 + wm + 16 * i + kq * 4;
      const int c  = n0 + wn + 16 * j + fr;
      const float bv = bias[c];
      #pragma unroll
      for (int ri = 0; ri < 4; ri++) {
        float val = acc[i][j][ri] + bv;
        const size_t idx = (size_t)(r0 + ri) * N + c;
        if (mode == 0) {
          ((bf16*)Cv)[idx] = f2b(val);
        } else if (mode == 1) {
          val = 0.5f * val * (1.0f + erff(val * 0.70710678118654752f));
          ((bf16*)Cv)[idx] = f2b(val);
        } else {
          ((float*)Cv)[idx] = val + res[idx];
        }
      }
    }
  }
}

// ---------------------------------------------------------------------------
// KtV[h] = scale * K_h^T @ V_h from fused qkv buffer (bf16, ld=2304).
// Grid (H, S/64); fp32 atomic accumulate into zeroed ktv.
// ---------------------------------------------------------------------------
__global__ __launch_bounds__(256) void ktv_kernel(
    const bf16* __restrict__ qkv, float* __restrict__ ktvb) {
  int h = blockIdx.x, c = blockIdx.y;
  __shared__ float Ks[8][64];
  __shared__ float Vs[8][64];
  int tid = threadIdx.x;
  int i  = tid >> 2;
  int j0 = (tid & 3) * 16;
  int rr = tid >> 4, cc = (tid & 15) * 4;
  float acc[16] = {};
  int sbase = c * 64;
  for (int so = 0; so < 64; so += 8) {
    const bf16* src = (rr < 8)
        ? (qkv + (size_t)(sbase + so + rr) * 2304 + 768 + h * DHH + cc)
        : (qkv + (size_t)(sbase + so + rr - 8) * 2304 + 1536 + h * DHH + cc);
    short4 s4 = *(const short4*)src;
    float f0 = b2f(s4.x), f1 = b2f(s4.y), f2v = b2f(s4.z), f3 = b2f(s4.w);
    if (rr < 8) { Ks[rr][cc] = f0; Ks[rr][cc+1] = f1; Ks[rr][cc+2] = f2v; Ks[rr][cc+3] = f3; }
    else        { Vs[rr-8][cc] = f0; Vs[rr-8][cc+1] = f1; Vs[rr-8][cc+2] = f2v; Vs[rr-8][cc+3] = f3; }
    __syncthreads();
    #pragma unroll
    for (int s = 0; s < 8; s++) {
      float kv = Ks[s][i];
      #pragma unroll
      for (int j = 0; j < 16; j++) acc[j] += kv * Vs[s][j0 + j];
    }
    __syncthreads();
  }
  float* dst = ktvb + h * DHH * DHH + i * DHH + j0;
  #pragma unroll
  for (int j = 0; j < 16; j++) atomicAdd(dst + j, acc[j] * 0.125f);
}

// ---------------------------------------------------------------------------
// ab[:, h*64:+64] = Q_h @ KtV_h   (Q bf16 from qkv ld=2304, KtV fp32, out bf16)
// ---------------------------------------------------------------------------
__global__ __launch_bounds__(256) void qktv_kernel(
    const bf16* __restrict__ qkv, const float* __restrict__ ktvb,
    bf16* __restrict__ ab) {
  int h = blockIdx.y, m0 = blockIdx.x * 32;
  __shared__ float Ks[64 * 64];
  __shared__ float Qs[32][65];
  int tid = threadIdx.x;
  const float* kt = ktvb + h * DHH * DHH;
  #pragma unroll
  for (int it = 0; it < 4; it++) {
    int idx = it * 1024 + tid * 4;
    *(float4*)&Ks[idx] = *(const float4*)&kt[idx];
  }
  #pragma unroll
  for (int it = 0; it < 2; it++) {
    int idx = it * 1024 + tid * 4;
    int r = idx >> 6, ccol = idx & 63;
    short4 s4 = *(const short4*)&qkv[(size_t)(m0 + r) * 2304 + h * DHH + ccol];
    Qs[r][ccol] = b2f(s4.x); Qs[r][ccol+1] = b2f(s4.y);
    Qs[r][ccol+2] = b2f(s4.z); Qs[r][ccol+3] = b2f(s4.w);
  }
  __syncthreads();
  int r = tid >> 3, c0 = (tid & 7) * 8;
  float acc[8] = {};
  #pragma unroll 8
  for (int kk = 0; kk < 64; kk++) {
    float qv = Qs[r][kk];
    float4 b0 = *(const float4*)&Ks[kk * 64 + c0];
    float4 b1 = *(const float4*)&Ks[kk * 64 + c0 + 4];
    acc[0] += qv * b0.x; acc[1] += qv * b0.y; acc[2] += qv * b0.z; acc[3] += qv * b0.w;
    acc[4] += qv * b1.x; acc[5] += qv * b1.y; acc[6] += qv * b1.z; acc[7] += qv * b1.w;
  }
  bf16* dst = ab + (size_t)(m0 + r) * EE + h * DHH + c0;
  #pragma unroll
  for (int j = 0; j < 8; j++) dst[j] = f2b(acc[j]);
}

// ---------------------------------------------------------------------------
extern "C" void kernel_launch(void* const* d_in, const int* in_sizes, int n_in,
                              void* d_out, int out_size, void* d_ws, size_t ws_size,
                              hipStream_t stream) {
  const float* emb  = (const float*)d_in[0];
  const float* wpe  = (const float*)d_in[1];
  const float* ln1g = (const float*)d_in[2];
  const float* ln1b = (const float*)d_in[3];
  const float* Wq   = (const float*)d_in[4];
  const float* bq   = (const float*)d_in[5];
  const float* Wk   = (const float*)d_in[6];
  const float* bk   = (const float*)d_in[7];
  const float* Wv   = (const float*)d_in[8];
  const float* bv   = (const float*)d_in[9];
  const float* Wo   = (const float*)d_in[10];
  const float* bo   = (const float*)d_in[11];
  const float* ln2g = (const float*)d_in[12];
  const float* ln2b = (const float*)d_in[13];
  const float* W1   = (const float*)d_in[14];
  const float* b1   = (const float*)d_in[15];
  const float* W2   = (const float*)d_in[16];
  const float* b2   = (const float*)d_in[17];
  const float* lnfg = (const float*)d_in[18];
  const float* lnfb = (const float*)d_in[19];

  // Workspace layout (~49 MB, all 16B-aligned)
  char* w = (char*)d_ws;
  float* x      = (float*)w;  w += (size_t)SS * EE * 4;
  bf16*  hb     = (bf16*)w;   w += (size_t)SS * EE * 2;
  bf16*  qkv    = (bf16*)w;   w += (size_t)SS * 2304 * 2;
  bf16*  ab     = (bf16*)w;   w += (size_t)SS * EE * 2;
  bf16*  mb2    = (bf16*)w;   w += (size_t)SS * FFF * 2;
  float* ktvb   = (float*)w;  w += (size_t)HH * DHH * DHH * 4;
  bf16*  Wqkv_t = (bf16*)w;   w += (size_t)2304 * EE * 2;
  bf16*  Wo_t   = (bf16*)w;   w += (size_t)EE * EE * 2;
  bf16*  W1_t   = (bf16*)w;   w += (size_t)FFF * EE * 2;
  bf16*  W2_t   = (bf16*)w;   w += (size_t)EE * FFF * 2;
  float* bqkv   = (float*)w;  w += 2304 * 4;

  dim3 blk(256);
  add_embed_kernel<<<SS * EE / 1024, blk, 0, stream>>>(emb, wpe, x);

  for (int l = 0; l < LL; l++) {
    const size_t wofs = (size_t)l * EE * EE;
    // weight conversion (fp32 [K][N] -> bf16 [N][K]) for this layer
    transpose_bf16_kernel<<<dim3(24, 24), blk, 0, stream>>>(Wq + wofs, Wqkv_t, EE, EE);
    transpose_bf16_kernel<<<dim3(24, 24), blk, 0, stream>>>(Wk + wofs, Wqkv_t + (size_t)768 * EE, EE, EE);
    transpose_bf16_kernel<<<dim3(24, 24), blk, 0, stream>>>(Wv + wofs, Wqkv_t + (size_t)1536 * EE, EE, EE);
    transpose_bf16_kernel<<<dim3(24, 24), blk, 0, stream>>>(Wo + wofs, Wo_t, EE, EE);
    transpose_bf16_kernel<<<dim3(96, 24), blk, 0, stream>>>(W1 + (size_t)l * EE * FFF, W1_t, EE, FFF);
    transpose_bf16_kernel<<<dim3(24, 96), blk, 0, stream>>>(W2 + (size_t)l * FFF * EE, W2_t, FFF, EE);
    concat_bias_kernel<<<9, blk, 0, stream>>>(bq + l * EE, bk + l * EE, bv + l * EE, bqkv);

    ln_kernel_t<bf16><<<SS, blk, 0, stream>>>(x, ln1g + l * EE, ln1b + l * EE, hb);
    // fused QKV: [2048x768] @ [768x2304] -> qkv bf16
    gemm_bf16_kernel<<<dim3(2304 / 128, SS / 128), blk, 0, stream>>>(
        hb, Wqkv_t, bqkv, nullptr, qkv, EE, 2304, 0);
    hipMemsetAsync(ktvb, 0, HH * DHH * DHH * sizeof(float), stream);
    ktv_kernel<<<dim3(HH, SS / 64), blk, 0, stream>>>(qkv, ktvb);
    qktv_kernel<<<dim3(SS / 32, HH), blk, 0, stream>>>(qkv, ktvb, ab);
    // O-projection + residual -> x fp32
    gemm_bf16_kernel<<<dim3(EE / 128, SS / 128), blk, 0, stream>>>(
        ab, Wo_t, bo + l * EE, x, x, EE, EE, 2);
    ln_kernel_t<bf16><<<SS, blk, 0, stream>>>(x, ln2g + l * EE, ln2b + l * EE, hb);
    // FF1 + GELU -> mb2 bf16
    gemm_bf16_kernel<<<dim3(FFF / 128, SS / 128), blk, 0, stream>>>(
        hb, W1_t, b1 + l * FFF, nullptr, mb2, EE, FFF, 1);
    // FF2 + residual -> x fp32
    gemm_bf16_kernel<<<dim3(EE / 128, SS / 128), blk, 0, stream>>>(
        mb2, W2_t, b2 + l * EE, x, x, FFF, EE, 2);
  }
  ln_kernel_t<float><<<SS, blk, 0, stream>>>(x, lnfg, lnfb, (float*)d_out);
}

// Round 3
// 872.739 us; speedup vs baseline: 3.0735x; 1.5787x over previous
//
#include <hip/hip_runtime.h>
#include <hip/hip_bf16.h>
#include <math.h>

#define SS 2048
#define EE 768
#define HH 12
#define DHH 64
#define FFF 3072
#define LL 4

typedef __hip_bfloat16 bf16;
typedef __attribute__((ext_vector_type(8))) short short8;
typedef __attribute__((ext_vector_type(4))) float f32x4;

__device__ __forceinline__ float b2f(short u) {
  union { unsigned int i; float f; } v;
  v.i = ((unsigned int)(unsigned short)u) << 16;
  return v.f;
}
__device__ __forceinline__ bf16 f2b(float f) { return __float2bfloat16(f); }

__device__ __forceinline__ void async_ld16(const void* g, void* l) {
  __builtin_amdgcn_global_load_lds(
      (const __attribute__((address_space(1))) void*)g,
      (__attribute__((address_space(3))) void*)l, 16, 0, 0);
}

// ---------------------------------------------------------------------------
// x = inputs_embeds + wpe
// ---------------------------------------------------------------------------
__global__ __launch_bounds__(256) void add_embed_kernel(
    const float* __restrict__ a, const float* __restrict__ b, float* __restrict__ out) {
  int i = (blockIdx.x * 256 + threadIdx.x) * 4;
  float4 av = *(const float4*)(a + i);
  float4 bv = *(const float4*)(b + i);
  float4 o; o.x = av.x + bv.x; o.y = av.y + bv.y; o.z = av.z + bv.z; o.w = av.w + bv.w;
  *(float4*)(out + i) = o;
}

// ---------------------------------------------------------------------------
// Fused (optional: bias + split-K partial reduce + x writeback) + LayerNorm.
// x_new = x + bias + sum_p part[p];  x (in place) = x_new;  out = LN(x_new).
// ---------------------------------------------------------------------------
template <typename OutT>
__global__ __launch_bounds__(256) void ln_fused_kernel(
    float* x, const float* __restrict__ bias, const float* __restrict__ part,
    int nparts, const float* __restrict__ g, const float* __restrict__ bta,
    int writeback, OutT* __restrict__ out) {
  int row = blockIdx.x;
  int tid = threadIdx.x;
  float* xr = x + (size_t)row * EE;
  float v0 = xr[tid], v1 = xr[tid + 256], v2 = xr[tid + 512];
  if (bias) { v0 += bias[tid]; v1 += bias[tid + 256]; v2 += bias[tid + 512]; }
  for (int p = 0; p < nparts; p++) {
    const float* pr = part + (size_t)p * SS * EE + (size_t)row * EE;
    v0 += pr[tid]; v1 += pr[tid + 256]; v2 += pr[tid + 512];
  }
  if (writeback) { xr[tid] = v0; xr[tid + 256] = v1; xr[tid + 512] = v2; }
  float s  = v0 + v1 + v2;
  float s2 = v0 * v0 + v1 * v1 + v2 * v2;
  #pragma unroll
  for (int off = 32; off >= 1; off >>= 1) {
    s  += __shfl_down(s,  off);
    s2 += __shfl_down(s2, off);
  }
  __shared__ float red[8];
  __shared__ float mb[2];
  int lane = tid & 63, wid = tid >> 6;
  if (lane == 0) { red[wid] = s; red[4 + wid] = s2; }
  __syncthreads();
  if (tid == 0) {
    float ts  = red[0] + red[1] + red[2] + red[3];
    float ts2 = red[4] + red[5] + red[6] + red[7];
    float mu  = ts * (1.0f / EE);
    float var = ts2 * (1.0f / EE) - mu * mu;
    mb[0] = mu; mb[1] = rsqrtf(var + 1e-5f);
  }
  __syncthreads();
  float mu = mb[0], rs = mb[1];
  OutT* orow = out + (size_t)row * EE;
  float o0 = (v0 - mu) * rs * g[tid]       + bta[tid];
  float o1 = (v1 - mu) * rs * g[tid + 256] + bta[tid + 256];
  float o2 = (v2 - mu) * rs * g[tid + 512] + bta[tid + 512];
  if constexpr (sizeof(OutT) == 4) {
    orow[tid] = o0; orow[tid + 256] = o1; orow[tid + 512] = o2;
  } else {
    orow[tid] = f2b(o0); orow[tid + 256] = f2b(o1); orow[tid + 512] = f2b(o2);
  }
}

// ---------------------------------------------------------------------------
// Tiled transpose + fp32->bf16: src[K][N] f32 -> dst[N][K] bf16
// ---------------------------------------------------------------------------
__global__ __launch_bounds__(256) void transpose_bf16_kernel(
    const float* __restrict__ src, bf16* __restrict__ dst, int K, int N) {
  __shared__ float tile[32][33];
  int n0 = blockIdx.x * 32, k0 = blockIdx.y * 32;
  int tx = threadIdx.x & 31, ty = threadIdx.x >> 5;
  #pragma unroll
  for (int r = 0; r < 32; r += 8)
    tile[ty + r][tx] = src[(size_t)(k0 + ty + r) * N + n0 + tx];
  __syncthreads();
  #pragma unroll
  for (int r = 0; r < 32; r += 8)
    dst[(size_t)(n0 + ty + r) * K + k0 + tx] = f2b(tile[tx][ty + r]);
}

__global__ __launch_bounds__(256) void concat_bias_kernel(
    const float* __restrict__ bq, const float* __restrict__ bk,
    const float* __restrict__ bv, float* __restrict__ out) {
  int i = blockIdx.x * 256 + threadIdx.x;
  out[i] = (i < 768) ? bq[i] : (i < 1536 ? bk[i - 768] : bv[i - 1536]);
}

// ---------------------------------------------------------------------------
// bf16 MFMA GEMM: C = A[M,K] @ Bt[N,K]^T (+bias). 128x128 tile, BK=32.
// mode 0: bias, store bf16    mode 1: bias, exact GELU, store bf16
// mode 3: split-K partial fp32 (z = blockIdx.z), no bias
// ---------------------------------------------------------------------------
__global__ __launch_bounds__(256) void gemm_bf16_kernel(
    const bf16* __restrict__ A, const bf16* __restrict__ Bt,
    const float* __restrict__ bias, void* __restrict__ Cv,
    int K, int N, int mode, int Ksplit) {
  __shared__ __align__(16) short As[128 * 32];
  __shared__ __align__(16) short Bs[128 * 32];
  const int t = threadIdx.x;
  const int wave = t >> 6, lane = t & 63;
  const int m0 = blockIdx.y * 128, n0 = blockIdx.x * 128;
  const int z = blockIdx.z;
  const int kBeg = z * Ksplit, kEnd = kBeg + Ksplit;

  const bf16* Ag0 = A  + (size_t)(m0 + (t >> 2)) * K + (t & 3) * 8;
  const bf16* Ag1 = A  + (size_t)(m0 + 64 + (t >> 2)) * K + (t & 3) * 8;
  const bf16* Bg0 = Bt + (size_t)(n0 + (t >> 2)) * K + (t & 3) * 8;
  const bf16* Bg1 = Bt + (size_t)(n0 + 64 + (t >> 2)) * K + (t & 3) * 8;
  short* Asw0 = As + wave * 512;
  short* Asw1 = As + 2048 + wave * 512;
  short* Bsw0 = Bs + wave * 512;
  short* Bsw1 = Bs + 2048 + wave * 512;

  const int fr = lane & 15, kq = lane >> 4;
  const int wm = (wave >> 1) * 64, wn = (wave & 1) * 64;
  f32x4 acc[4][4] = {};

  for (int k0 = kBeg; k0 < kEnd; k0 += 32) {
    async_ld16(Ag0 + k0, Asw0);
    async_ld16(Ag1 + k0, Asw1);
    async_ld16(Bg0 + k0, Bsw0);
    async_ld16(Bg1 + k0, Bsw1);
    __syncthreads();
    short8 a[4], b[4];
    #pragma unroll
    for (int i = 0; i < 4; i++)
      a[i] = *(const short8*)(As + (wm + 16 * i + fr) * 32 + kq * 8);
    #pragma unroll
    for (int j = 0; j < 4; j++)
      b[j] = *(const short8*)(Bs + (wn + 16 * j + fr) * 32 + kq * 8);
    #pragma unroll
    for (int i = 0; i < 4; i++)
      #pragma unroll
      for (int j = 0; j < 4; j++)
        acc[i][j] = __builtin_amdgcn_mfma_f32_16x16x32_bf16(a[i], b[j], acc[i][j], 0, 0, 0);
    __syncthreads();
  }

  // C/D layout: col = lane&15, row = (lane>>4)*4 + reg
  #pragma unroll
  for (int i = 0; i < 4; i++) {
    #pragma unroll
    for (int j = 0; j < 4; j++) {
      const int r0 = m0 + wm + 16 * i + kq * 4;
      const int c  = n0 + wn + 16 * j + fr;
      const float bv = (mode == 3) ? 0.0f : bias[c];
      #pragma unroll
      for (int ri = 0; ri < 4; ri++) {
        float val = acc[i][j][ri] + bv;
        const size_t idx = (size_t)(r0 + ri) * N + c;
        if (mode == 0) {
          ((bf16*)Cv)[idx] = f2b(val);
        } else if (mode == 1) {
          val = 0.5f * val * (1.0f + erff(val * 0.70710678118654752f));
          ((bf16*)Cv)[idx] = f2b(val);
        } else {
          ((float*)Cv)[(size_t)z * SS * N + idx] = val;
        }
      }
    }
  }
}

// ---------------------------------------------------------------------------
// KtV phase 1: per-split partial K_h^T @ V_h (no atomics, plain stores).
// Grid (H, 32). part[(c*H + h)][i][j], 64 s-rows per split.
// ---------------------------------------------------------------------------
__global__ __launch_bounds__(256) void ktv_part_kernel(
    const bf16* __restrict__ qkv, float* __restrict__ part) {
  int h = blockIdx.x, c = blockIdx.y;
  __shared__ float Ks[8][64];
  __shared__ float Vs[8][64];
  int tid = threadIdx.x;
  int i  = tid >> 2;
  int j0 = (tid & 3) * 16;
  int rr = tid >> 4, cc = (tid & 15) * 4;
  float acc[16] = {};
  int sbase = c * 64;
  for (int so = 0; so < 64; so += 8) {
    const bf16* src = (rr < 8)
        ? (qkv + (size_t)(sbase + so + rr) * 2304 + 768 + h * DHH + cc)
        : (qkv + (size_t)(sbase + so + rr - 8) * 2304 + 1536 + h * DHH + cc);
    short4 s4 = *(const short4*)src;
    float f0 = b2f(s4.x), f1 = b2f(s4.y), f2v = b2f(s4.z), f3 = b2f(s4.w);
    if (rr < 8) { Ks[rr][cc] = f0; Ks[rr][cc+1] = f1; Ks[rr][cc+2] = f2v; Ks[rr][cc+3] = f3; }
    else        { Vs[rr-8][cc] = f0; Vs[rr-8][cc+1] = f1; Vs[rr-8][cc+2] = f2v; Vs[rr-8][cc+3] = f3; }
    __syncthreads();
    #pragma unroll
    for (int s = 0; s < 8; s++) {
      float kv = Ks[s][i];
      #pragma unroll
      for (int j = 0; j < 16; j++) acc[j] += kv * Vs[s][j0 + j];
    }
    __syncthreads();
  }
  float* dst = part + ((size_t)c * HH + h) * (DHH * DHH) + i * DHH + j0;
  #pragma unroll
  for (int j = 0; j < 16; j += 4) {
    float4 o; o.x = acc[j]; o.y = acc[j+1]; o.z = acc[j+2]; o.w = acc[j+3];
    *(float4*)(dst + j) = o;
  }
}

// KtV phase 2: ktv[g] = 0.125 * sum_c part[c][g].  Grid 192 x 256.
__global__ __launch_bounds__(256) void ktv_reduce_kernel(
    const float* __restrict__ part, float* __restrict__ ktvb) {
  int g = blockIdx.x * 256 + threadIdx.x;
  float s = 0.f;
  #pragma unroll 8
  for (int c = 0; c < 32; c++) s += part[(size_t)c * (HH * DHH * DHH) + g];
  ktvb[g] = s * 0.125f;
}

// ---------------------------------------------------------------------------
// ab[:, h*64:+64] = Q_h @ KtV_h
// ---------------------------------------------------------------------------
__global__ __launch_bounds__(256) void qktv_kernel(
    const bf16* __restrict__ qkv, const float* __restrict__ ktvb,
    bf16* __restrict__ ab) {
  int h = blockIdx.y, m0 = blockIdx.x * 32;
  __shared__ float Ks[64 * 64];
  __shared__ float Qs[32][65];
  int tid = threadIdx.x;
  const float* kt = ktvb + h * DHH * DHH;
  #pragma unroll
  for (int it = 0; it < 4; it++) {
    int idx = it * 1024 + tid * 4;
    *(float4*)&Ks[idx] = *(const float4*)&kt[idx];
  }
  #pragma unroll
  for (int it = 0; it < 2; it++) {
    int idx = it * 1024 + tid * 4;
    int r = idx >> 6, ccol = idx & 63;
    short4 s4 = *(const short4*)&qkv[(size_t)(m0 + r) * 2304 + h * DHH + ccol];
    Qs[r][ccol] = b2f(s4.x); Qs[r][ccol+1] = b2f(s4.y);
    Qs[r][ccol+2] = b2f(s4.z); Qs[r][ccol+3] = b2f(s4.w);
  }
  __syncthreads();
  int r = tid >> 3, c0 = (tid & 7) * 8;
  float acc[8] = {};
  #pragma unroll 8
  for (int kk = 0; kk < 64; kk++) {
    float qv = Qs[r][kk];
    float4 b0 = *(const float4*)&Ks[kk * 64 + c0];
    float4 b1 = *(const float4*)&Ks[kk * 64 + c0 + 4];
    acc[0] += qv * b0.x; acc[1] += qv * b0.y; acc[2] += qv * b0.z; acc[3] += qv * b0.w;
    acc[4] += qv * b1.x; acc[5] += qv * b1.y; acc[6] += qv * b1.z; acc[7] += qv * b1.w;
  }
  bf16* dst = ab + (size_t)(m0 + r) * EE + h * DHH + c0;
  #pragma unroll
  for (int j = 0; j < 8; j++) dst[j] = f2b(acc[j]);
}

// ---------------------------------------------------------------------------
extern "C" void kernel_launch(void* const* d_in, const int* in_sizes, int n_in,
                              void* d_out, int out_size, void* d_ws, size_t ws_size,
                              hipStream_t stream) {
  const float* emb  = (const float*)d_in[0];
  const float* wpe  = (const float*)d_in[1];
  const float* ln1g = (const float*)d_in[2];
  const float* ln1b = (const float*)d_in[3];
  const float* Wq   = (const float*)d_in[4];
  const float* bq   = (const float*)d_in[5];
  const float* Wk   = (const float*)d_in[6];
  const float* bk   = (const float*)d_in[7];
  const float* Wv   = (const float*)d_in[8];
  const float* bv   = (const float*)d_in[9];
  const float* Wo   = (const float*)d_in[10];
  const float* bo   = (const float*)d_in[11];
  const float* ln2g = (const float*)d_in[12];
  const float* ln2b = (const float*)d_in[13];
  const float* W1   = (const float*)d_in[14];
  const float* b1   = (const float*)d_in[15];
  const float* W2   = (const float*)d_in[16];
  const float* b2   = (const float*)d_in[17];
  const float* lnfg = (const float*)d_in[18];
  const float* lnfb = (const float*)d_in[19];

  // Workspace (~49.7 MB) with lifetime-based aliasing:
  //   ab aliases ktv_part (part dead after reduce, ab written after)
  //   mb2 aliases qkv (qkv dead after qktv, mb2 written in FF1 after)
  char* w = (char*)d_ws;
  float* x        = (float*)w;  w += (size_t)SS * EE * 4;       // 6.29 MB
  bf16*  hb       = (bf16*)w;   w += (size_t)SS * EE * 2;       // 3.15 MB
  bf16*  Wt       = (bf16*)w;   w += (size_t)FFF * EE * 2;      // 4.72 MB (shared)
  float* bqkv     = (float*)w;  w += 2304 * 4;
  float* ktvb     = (float*)w;  w += HH * DHH * DHH * 4;        // 0.20 MB
  float* ktv_part = (float*)w;
  bf16*  ab       = (bf16*)w;   w += (size_t)32 * HH * DHH * DHH * 4;  // 6.29 MB
  bf16*  qkv      = (bf16*)w;
  bf16*  mb2      = (bf16*)w;   w += (size_t)SS * FFF * 2;      // 12.58 MB
  float* cpart    = (float*)w;  w += (size_t)3 * SS * EE * 4;   // 18.87 MB

  dim3 blk(256);
  add_embed_kernel<<<SS * EE / 1024, blk, 0, stream>>>(emb, wpe, x);

  for (int l = 0; l < LL; l++) {
    const size_t wofs = (size_t)l * EE * EE;
    // LN1: layer 0 plain; layers 1..3 fused with FF2 partials + b2 of prev layer
    if (l == 0) {
      ln_fused_kernel<bf16><<<SS, blk, 0, stream>>>(
          x, nullptr, nullptr, 0, ln1g, ln1b, 0, hb);
    } else {
      ln_fused_kernel<bf16><<<SS, blk, 0, stream>>>(
          x, b2 + (l - 1) * EE, cpart, 3, ln1g + l * EE, ln1b + l * EE, 1, hb);
    }
    // QKV
    transpose_bf16_kernel<<<dim3(24, 24), blk, 0, stream>>>(Wq + wofs, Wt, EE, EE);
    transpose_bf16_kernel<<<dim3(24, 24), blk, 0, stream>>>(Wk + wofs, Wt + (size_t)768 * EE, EE, EE);
    transpose_bf16_kernel<<<dim3(24, 24), blk, 0, stream>>>(Wv + wofs, Wt + (size_t)1536 * EE, EE, EE);
    concat_bias_kernel<<<9, blk, 0, stream>>>(bq + l * EE, bk + l * EE, bv + l * EE, bqkv);
    gemm_bf16_kernel<<<dim3(18, 16, 1), blk, 0, stream>>>(
        hb, Wt, bqkv, qkv, EE, 2304, 0, EE);
    // linear attention: KtV then Q@KtV
    ktv_part_kernel<<<dim3(HH, 32), blk, 0, stream>>>(qkv, ktv_part);
    ktv_reduce_kernel<<<192, blk, 0, stream>>>(ktv_part, ktvb);
    qktv_kernel<<<dim3(SS / 32, HH), blk, 0, stream>>>(qkv, ktvb, ab);
    // O-projection: split-K=3 partials; bias+residual folded into LN2
    transpose_bf16_kernel<<<dim3(24, 24), blk, 0, stream>>>(Wo + wofs, Wt, EE, EE);
    gemm_bf16_kernel<<<dim3(6, 16, 3), blk, 0, stream>>>(
        ab, Wt, nullptr, cpart, EE, EE, 3, 256);
    ln_fused_kernel<bf16><<<SS, blk, 0, stream>>>(
        x, bo + l * EE, cpart, 3, ln2g + l * EE, ln2b + l * EE, 1, hb);
    // FF1 (+GELU)
    transpose_bf16_kernel<<<dim3(96, 24), blk, 0, stream>>>(W1 + (size_t)l * EE * FFF, Wt, EE, FFF);
    gemm_bf16_kernel<<<dim3(24, 16, 1), blk, 0, stream>>>(
        hb, Wt, b1 + l * FFF, mb2, EE, FFF, 1, EE);
    // FF2: split-K=3 partials; bias+residual folded into next LN
    transpose_bf16_kernel<<<dim3(24, 96), blk, 0, stream>>>(W2 + (size_t)l * FFF * EE, Wt, FFF, EE);
    gemm_bf16_kernel<<<dim3(6, 16, 3), blk, 0, stream>>>(
        mb2, Wt, nullptr, cpart, FFF, EE, 3, 1024);
  }
  ln_fused_kernel<float><<<SS, blk, 0, stream>>>(
      x, b2 + 3 * EE, cpart, 3, lnfg, lnfb, 0, (float*)d_out);
}

// Round 4
// 737.117 us; speedup vs baseline: 3.6390x; 1.1840x over previous
//
#include <hip/hip_runtime.h>
#include <hip/hip_bf16.h>
#include <math.h>

#define SS 2048
#define EE 768
#define HH 12
#define DHH 64
#define FFF 3072
#define LL 4

typedef __hip_bfloat16 bf16;
typedef __attribute__((ext_vector_type(8))) short short8;
typedef __attribute__((ext_vector_type(4))) float f32x4;

__device__ __forceinline__ float b2f(short u) {
  union { unsigned int i; float f; } v;
  v.i = ((unsigned int)(unsigned short)u) << 16;
  return v.f;
}
__device__ __forceinline__ bf16 f2b(float f) { return __float2bfloat16(f); }

__device__ __forceinline__ void async_ld16(const void* g, void* l) {
  __builtin_amdgcn_global_load_lds(
      (const __attribute__((address_space(1))) void*)g,
      (__attribute__((address_space(3))) void*)l, 16, 0, 0);
}

// ---------------------------------------------------------------------------
// x = inputs_embeds + wpe
// ---------------------------------------------------------------------------
__global__ __launch_bounds__(256) void add_embed_kernel(
    const float* __restrict__ a, const float* __restrict__ b, float* __restrict__ out) {
  int i = (blockIdx.x * 256 + threadIdx.x) * 4;
  float4 av = *(const float4*)(a + i);
  float4 bv = *(const float4*)(b + i);
  float4 o; o.x = av.x + bv.x; o.y = av.y + bv.y; o.z = av.z + bv.z; o.w = av.w + bv.w;
  *(float4*)(out + i) = o;
}

// ---------------------------------------------------------------------------
// Fused (bias + split-K partial reduce + x writeback) + LayerNorm
// ---------------------------------------------------------------------------
template <typename OutT>
__global__ __launch_bounds__(256) void ln_fused_kernel(
    float* x, const float* __restrict__ bias, const float* __restrict__ part,
    int nparts, const float* __restrict__ g, const float* __restrict__ bta,
    int writeback, OutT* __restrict__ out) {
  int row = blockIdx.x;
  int tid = threadIdx.x;
  float* xr = x + (size_t)row * EE;
  float v0 = xr[tid], v1 = xr[tid + 256], v2 = xr[tid + 512];
  if (bias) { v0 += bias[tid]; v1 += bias[tid + 256]; v2 += bias[tid + 512]; }
  for (int p = 0; p < nparts; p++) {
    const float* pr = part + (size_t)p * SS * EE + (size_t)row * EE;
    v0 += pr[tid]; v1 += pr[tid + 256]; v2 += pr[tid + 512];
  }
  if (writeback) { xr[tid] = v0; xr[tid + 256] = v1; xr[tid + 512] = v2; }
  float s  = v0 + v1 + v2;
  float s2 = v0 * v0 + v1 * v1 + v2 * v2;
  #pragma unroll
  for (int off = 32; off >= 1; off >>= 1) {
    s  += __shfl_down(s,  off);
    s2 += __shfl_down(s2, off);
  }
  __shared__ float red[8];
  __shared__ float mb[2];
  int lane = tid & 63, wid = tid >> 6;
  if (lane == 0) { red[wid] = s; red[4 + wid] = s2; }
  __syncthreads();
  if (tid == 0) {
    float ts  = red[0] + red[1] + red[2] + red[3];
    float ts2 = red[4] + red[5] + red[6] + red[7];
    float mu  = ts * (1.0f / EE);
    float var = ts2 * (1.0f / EE) - mu * mu;
    mb[0] = mu; mb[1] = rsqrtf(var + 1e-5f);
  }
  __syncthreads();
  float mu = mb[0], rs = mb[1];
  OutT* orow = out + (size_t)row * EE;
  float o0 = (v0 - mu) * rs * g[tid]       + bta[tid];
  float o1 = (v1 - mu) * rs * g[tid + 256] + bta[tid + 256];
  float o2 = (v2 - mu) * rs * g[tid + 512] + bta[tid + 512];
  if constexpr (sizeof(OutT) == 4) {
    orow[tid] = o0; orow[tid + 256] = o1; orow[tid + 512] = o2;
  } else {
    orow[tid] = f2b(o0); orow[tid + 256] = f2b(o1); orow[tid + 512] = f2b(o2);
  }
}

// ---------------------------------------------------------------------------
// ONE launch: transpose+bf16-convert ALL weights of ALL 4 layers.
// Per-layer dst layout (shorts): Wqkv_t[2304][768] @0, Wo_t[768][768] @1769472,
// W1_t[3072][768] @2359296, W2_t[768][3072] @4718592; layer stride 7077888.
// ---------------------------------------------------------------------------
__global__ __launch_bounds__(256) void transpose_all_kernel(
    const float* __restrict__ Wq, const float* __restrict__ Wk,
    const float* __restrict__ Wv, const float* __restrict__ Wo,
    const float* __restrict__ W1, const float* __restrict__ W2,
    bf16* __restrict__ WtAll) {
  __shared__ float tile[32][33];
  int bid = blockIdx.x;
  int l = bid / 6912, r = bid % 6912;
  bf16* base = WtAll + (size_t)l * 7077888;
  const float* src; bf16* dst; int K, N, rr;
  if (r < 1728) {
    int m = r / 576; rr = r % 576;
    src = (m == 0 ? Wq : m == 1 ? Wk : Wv) + (size_t)l * EE * EE;
    dst = base + (size_t)m * 589824; K = 768; N = 768;
  } else if (r < 2304) {
    rr = r - 1728; src = Wo + (size_t)l * EE * EE; dst = base + 1769472; K = 768; N = 768;
  } else if (r < 4608) {
    rr = r - 2304; src = W1 + (size_t)l * EE * FFF; dst = base + 2359296; K = 768; N = 3072;
  } else {
    rr = r - 4608; src = W2 + (size_t)l * FFF * EE; dst = base + 4718592; K = 3072; N = 768;
  }
  int ntiles = N / 32;
  int n0 = (rr % ntiles) * 32, k0 = (rr / ntiles) * 32;
  int tx = threadIdx.x & 31, ty = threadIdx.x >> 5;
  #pragma unroll
  for (int q = 0; q < 32; q += 8)
    tile[ty + q][tx] = src[(size_t)(k0 + ty + q) * N + n0 + tx];
  __syncthreads();
  #pragma unroll
  for (int q = 0; q < 32; q += 8)
    dst[(size_t)(n0 + ty + q) * K + k0 + tx] = f2b(tile[tx][ty + q]);
}

// all 4 layers' q,k,v biases -> bqkv_all[l][2304]. grid 36.
__global__ __launch_bounds__(256) void concat_bias_all_kernel(
    const float* __restrict__ bq, const float* __restrict__ bk,
    const float* __restrict__ bv, float* __restrict__ out) {
  int g = blockIdx.x * 256 + threadIdx.x;
  int l = g / 2304, i = g % 2304;
  out[g] = (i < 768) ? bq[l * 768 + i]
         : (i < 1536 ? bk[l * 768 + i - 768] : bv[l * 768 + i - 1536]);
}

// ---------------------------------------------------------------------------
// bf16 MFMA GEMM: C = A[M,K] @ Bt[N,K]^T (+bias). 128x128 tile, BK=64,
// XOR-swizzled k-chunks (global-side swizzle; LDS side p = c ^ (row&7)).
// mode 0: bias->bf16   mode 1: bias+GELU->bf16   mode 3: split-K fp32 partial
// ---------------------------------------------------------------------------
__global__ __launch_bounds__(256) void gemm_bf16_kernel(
    const bf16* __restrict__ A, const bf16* __restrict__ Bt,
    const float* __restrict__ bias, void* __restrict__ Cv,
    int K, int N, int mode, int Ksplit) {
  __shared__ __align__(16) short As[128 * 64];   // [row][64 k] swizzled
  __shared__ __align__(16) short Bs[128 * 64];
  const int t = threadIdx.x;
  const int wave = t >> 6, lane = t & 63;
  const int m0 = blockIdx.y * 128, n0 = blockIdx.x * 128;
  const int z = blockIdx.z;
  const int kBeg = z * Ksplit, kEnd = kBeg + Ksplit;

  const int srow = t >> 3;                   // 0..31 (row within 32-row call)
  const int sw   = (t & 7) ^ (srow & 7);     // global k-chunk this thread loads
  const bf16* Ag = A  + (size_t)(m0 + srow) * K + sw * 8;
  const bf16* Bg = Bt + (size_t)(n0 + srow) * K + sw * 8;

  const int fr = lane & 15, kq = lane >> 4;
  const int wm = (wave >> 1) * 64, wn = (wave & 1) * 64;
  f32x4 acc[4][4] = {};

  for (int k0 = kBeg; k0 < kEnd; k0 += 64) {
    #pragma unroll
    for (int c = 0; c < 4; c++) {
      async_ld16(Ag + (size_t)(32 * c) * K + k0, As + c * 2048 + wave * 512);
      async_ld16(Bg + (size_t)(32 * c) * K + k0, Bs + c * 2048 + wave * 512);
    }
    __syncthreads();
    #pragma unroll
    for (int s = 0; s < 2; s++) {
      short8 a[4], b[4];
      #pragma unroll
      for (int i = 0; i < 4; i++) {
        int r = wm + 16 * i + fr;
        int p = (kq + 4 * s) ^ (r & 7);
        a[i] = *(const short8*)(As + r * 64 + p * 8);
      }
      #pragma unroll
      for (int j = 0; j < 4; j++) {
        int r = wn + 16 * j + fr;
        int p = (kq + 4 * s) ^ (r & 7);
        b[j] = *(const short8*)(Bs + r * 64 + p * 8);
      }
      #pragma unroll
      for (int i = 0; i < 4; i++)
        #pragma unroll
        for (int j = 0; j < 4; j++)
          acc[i][j] = __builtin_amdgcn_mfma_f32_16x16x32_bf16(a[i], b[j], acc[i][j], 0, 0, 0);
    }
    __syncthreads();
  }

  // C/D layout: col = lane&15, row = (lane>>4)*4 + reg
  #pragma unroll
  for (int i = 0; i < 4; i++) {
    #pragma unroll
    for (int j = 0; j < 4; j++) {
      const int r0 = m0 + wm + 16 * i + kq * 4;
      const int c  = n0 + wn + 16 * j + fr;
      const float bv = (mode == 3) ? 0.0f : bias[c];
      #pragma unroll
      for (int ri = 0; ri < 4; ri++) {
        float val = acc[i][j][ri] + bv;
        const size_t idx = (size_t)(r0 + ri) * N + c;
        if (mode == 0) {
          ((bf16*)Cv)[idx] = f2b(val);
        } else if (mode == 1) {
          val = 0.5f * val * (1.0f + erff(val * 0.70710678118654752f));
          ((bf16*)Cv)[idx] = f2b(val);
        } else {
          ((float*)Cv)[(size_t)z * SS * N + idx] = val;
        }
      }
    }
  }
}

// ---------------------------------------------------------------------------
// kvT[y][d][s] = qkv[s][768 + y*64 + d]  (y 0..11 = K heads, 12..23 = V heads)
// grid (32 s-tiles, 24). 64x64 bf16 LDS transpose.
// ---------------------------------------------------------------------------
__global__ __launch_bounds__(256) void kvt_kernel(
    const bf16* __restrict__ qkv, bf16* __restrict__ kvT) {
  __shared__ short tile[64][65];
  int s0 = blockIdx.x * 64;
  int y  = blockIdx.y;
  int t = threadIdx.x;
  const short* src = (const short*)qkv + 768 + y * 64;
  #pragma unroll
  for (int it = 0; it < 4; it++) {
    int idx = it * 1024 + t * 4;
    int r = idx >> 6, c = idx & 63;
    short4 v = *(const short4*)(src + (size_t)(s0 + r) * 2304 + c);
    tile[r][c] = v.x; tile[r][c + 1] = v.y; tile[r][c + 2] = v.z; tile[r][c + 3] = v.w;
  }
  __syncthreads();
  #pragma unroll
  for (int it = 0; it < 4; it++) {
    int idx = it * 1024 + t * 4;
    int d = idx >> 6, s = idx & 63;
    short4 o;
    o.x = tile[s][d]; o.y = tile[s + 1][d]; o.z = tile[s + 2][d]; o.w = tile[s + 3][d];
    *(short4*)((short*)kvT + (size_t)(y * 64 + d) * 2048 + s0 + s) = o;
  }
}

// ---------------------------------------------------------------------------
// KtV partials via MFMA, barrier/LDS-free. grid (12 h, 8), 4 waves/block;
// wave = s-chunk of 64. part[(chunk*12+h)][d1][d2] fp32.
// ---------------------------------------------------------------------------
__global__ __launch_bounds__(256) void ktv_mfma_kernel(
    const bf16* __restrict__ kvT, float* __restrict__ part) {
  const int h = blockIdx.x;
  const int lane = threadIdx.x & 63, wave = threadIdx.x >> 6;
  const int chunk = blockIdx.y * 4 + wave;
  const int s0 = chunk * 64;
  const int fr = lane & 15, kq = lane >> 4;
  const short* kT = (const short*)kvT + (size_t)h * 64 * 2048;          // A: [d1][s]
  const short* vT = (const short*)kvT + (size_t)(768 + h * 64) * 2048;  // Bt: [d2][s]
  f32x4 acc[4][4] = {};
  #pragma unroll
  for (int s = 0; s < 2; s++) {
    short8 a[4], b[4];
    #pragma unroll
    for (int i = 0; i < 4; i++)
      a[i] = *(const short8*)(kT + (size_t)(16 * i + fr) * 2048 + s0 + s * 32 + kq * 8);
    #pragma unroll
    for (int j = 0; j < 4; j++)
      b[j] = *(const short8*)(vT + (size_t)(16 * j + fr) * 2048 + s0 + s * 32 + kq * 8);
    #pragma unroll
    for (int i = 0; i < 4; i++)
      #pragma unroll
      for (int j = 0; j < 4; j++)
        acc[i][j] = __builtin_amdgcn_mfma_f32_16x16x32_bf16(a[i], b[j], acc[i][j], 0, 0, 0);
  }
  float* dst = part + (size_t)(chunk * 12 + h) * 4096;
  #pragma unroll
  for (int i = 0; i < 4; i++)
    #pragma unroll
    for (int j = 0; j < 4; j++)
      #pragma unroll
      for (int ri = 0; ri < 4; ri++)
        dst[(16 * i + kq * 4 + ri) * 64 + 16 * j + fr] = acc[i][j][ri];
}

// ktvT[h][d2][d1] bf16 = 0.125 * sum_c part[(c*12+h)][d1][d2]. grid 192.
__global__ __launch_bounds__(256) void ktv_reduce_kernel(
    const float* __restrict__ part, bf16* __restrict__ ktvT) {
  int g = blockIdx.x * 256 + threadIdx.x;
  int h = g >> 12, rem = g & 4095, d1 = rem >> 6, d2 = rem & 63;
  float s = 0.f;
  #pragma unroll 8
  for (int c = 0; c < 32; c++) s += part[(size_t)(c * 12 + h) * 4096 + rem];
  ktvT[((h << 6) | d2) * 64 + d1] = f2b(s * 0.125f);
}

// ---------------------------------------------------------------------------
// ab[s][h*64+d2] = Q_h[s][:] @ KtV_h  via MFMA, barrier/LDS-free.
// grid (8 m-quarters, 12 h), 4 waves/block; wave = 64 s-rows.
// ---------------------------------------------------------------------------
__global__ __launch_bounds__(256) void qktv_mfma_kernel(
    const bf16* __restrict__ qkv, const bf16* __restrict__ ktvT,
    bf16* __restrict__ ab) {
  const int h = blockIdx.y;
  const int lane = threadIdx.x & 63, wave = threadIdx.x >> 6;
  const int m0 = blockIdx.x * 256 + wave * 64;
  const int fr = lane & 15, kq = lane >> 4;
  const short* Q = (const short*)qkv + h * 64;              // [s][d1] ld 2304
  const short* B = (const short*)ktvT + (size_t)h * 4096;   // [d2][d1] ld 64
  f32x4 acc[4][4] = {};
  #pragma unroll
  for (int s = 0; s < 2; s++) {
    short8 a[4], b[4];
    #pragma unroll
    for (int i = 0; i < 4; i++)
      a[i] = *(const short8*)(Q + (size_t)(m0 + 16 * i + fr) * 2304 + s * 32 + kq * 8);
    #pragma unroll
    for (int j = 0; j < 4; j++)
      b[j] = *(const short8*)(B + (size_t)(16 * j + fr) * 64 + s * 32 + kq * 8);
    #pragma unroll
    for (int i = 0; i < 4; i++)
      #pragma unroll
      for (int j = 0; j < 4; j++)
        acc[i][j] = __builtin_amdgcn_mfma_f32_16x16x32_bf16(a[i], b[j], acc[i][j], 0, 0, 0);
  }
  #pragma unroll
  for (int i = 0; i < 4; i++)
    #pragma unroll
    for (int j = 0; j < 4; j++)
      #pragma unroll
      for (int ri = 0; ri < 4; ri++)
        ab[(size_t)(m0 + 16 * i + kq * 4 + ri) * EE + h * 64 + 16 * j + fr] =
            f2b(acc[i][j][ri]);
}

// ---------------------------------------------------------------------------
extern "C" void kernel_launch(void* const* d_in, const int* in_sizes, int n_in,
                              void* d_out, int out_size, void* d_ws, size_t ws_size,
                              hipStream_t stream) {
  const float* emb  = (const float*)d_in[0];
  const float* wpe  = (const float*)d_in[1];
  const float* ln1g = (const float*)d_in[2];
  const float* ln1b = (const float*)d_in[3];
  const float* Wq   = (const float*)d_in[4];
  const float* bq   = (const float*)d_in[5];
  const float* Wk   = (const float*)d_in[6];
  const float* bk   = (const float*)d_in[7];
  const float* Wv   = (const float*)d_in[8];
  const float* bv   = (const float*)d_in[9];
  const float* Wo   = (const float*)d_in[10];
  const float* bo   = (const float*)d_in[11];
  const float* ln2g = (const float*)d_in[12];
  const float* ln2b = (const float*)d_in[13];
  const float* W1   = (const float*)d_in[14];
  const float* b1   = (const float*)d_in[15];
  const float* W2   = (const float*)d_in[16];
  const float* b2   = (const float*)d_in[17];
  const float* lnfg = (const float*)d_in[18];
  const float* lnfb = (const float*)d_in[19];

  // Workspace (~113 MB of the 256 MiB d_ws)
  char* w = (char*)d_ws;
  bf16*  WtAll  = (bf16*)w;   w += (size_t)4 * 7077888 * 2;   // 56.6 MB
  float* bqkvA  = (float*)w;  w += (size_t)4 * 2304 * 4;
  float* x      = (float*)w;  w += (size_t)SS * EE * 4;       // 6.3 MB
  bf16*  hb     = (bf16*)w;   w += (size_t)SS * EE * 2;       // 3.1 MB
  bf16*  qkv    = (bf16*)w;                                    // 9.4 MB (aliases mb2)
  bf16*  mb2    = (bf16*)w;   w += (size_t)SS * FFF * 2;      // 12.6 MB
  bf16*  kvT    = (bf16*)w;   w += (size_t)24 * 64 * 2048 * 2;// 6.3 MB
  float* part   = (float*)w;  w += (size_t)32 * 12 * 4096 * 4;// 6.3 MB
  bf16*  ktvT   = (bf16*)w;   w += (size_t)12 * 4096 * 2;     // 0.1 MB
  bf16*  ab     = (bf16*)w;   w += (size_t)SS * EE * 2;       // 3.1 MB
  float* cpart  = (float*)w;  w += (size_t)3 * SS * EE * 4;   // 18.9 MB

  dim3 blk(256);
  transpose_all_kernel<<<27648, blk, 0, stream>>>(Wq, Wk, Wv, Wo, W1, W2, WtAll);
  concat_bias_all_kernel<<<36, blk, 0, stream>>>(bq, bk, bv, bqkvA);
  add_embed_kernel<<<SS * EE / 1024, blk, 0, stream>>>(emb, wpe, x);

  for (int l = 0; l < LL; l++) {
    bf16* Wl = WtAll + (size_t)l * 7077888;
    bf16* Wqkv_t = Wl;
    bf16* Wo_t   = Wl + 1769472;
    bf16* W1_t   = Wl + 2359296;
    bf16* W2_t   = Wl + 4718592;

    if (l == 0) {
      ln_fused_kernel<bf16><<<SS, blk, 0, stream>>>(
          x, nullptr, nullptr, 0, ln1g, ln1b, 0, hb);
    } else {
      ln_fused_kernel<bf16><<<SS, blk, 0, stream>>>(
          x, b2 + (l - 1) * EE, cpart, 3, ln1g + l * EE, ln1b + l * EE, 1, hb);
    }
    // fused QKV GEMM
    gemm_bf16_kernel<<<dim3(18, 16, 1), blk, 0, stream>>>(
        hb, Wqkv_t, bqkvA + l * 2304, qkv, EE, 2304, 0, EE);
    // linear attention (MFMA)
    kvt_kernel<<<dim3(32, 24), blk, 0, stream>>>(qkv, kvT);
    ktv_mfma_kernel<<<dim3(HH, 8), blk, 0, stream>>>(kvT, part);
    ktv_reduce_kernel<<<192, blk, 0, stream>>>(part, ktvT);
    qktv_mfma_kernel<<<dim3(8, HH), blk, 0, stream>>>(qkv, ktvT, ab);
    // O-projection split-K=3; bias+residual folded into LN2
    gemm_bf16_kernel<<<dim3(6, 16, 3), blk, 0, stream>>>(
        ab, Wo_t, nullptr, cpart, EE, EE, 3, 256);
    ln_fused_kernel<bf16><<<SS, blk, 0, stream>>>(
        x, bo + l * EE, cpart, 3, ln2g + l * EE, ln2b + l * EE, 1, hb);
    // FF1 + GELU
    gemm_bf16_kernel<<<dim3(24, 16, 1), blk, 0, stream>>>(
        hb, W1_t, b1 + l * FFF, mb2, EE, FFF, 1, EE);
    // FF2 split-K=3; bias+residual folded into next LN
    gemm_bf16_kernel<<<dim3(6, 16, 3), blk, 0, stream>>>(
        mb2, W2_t, nullptr, cpart, FFF, EE, 3, 1024);
  }
  ln_fused_kernel<float><<<SS, blk, 0, stream>>>(
      x, b2 + 3 * EE, cpart, 3, lnfg, lnfb, 0, (float*)d_out);
}

// Round 5
// 729.019 us; speedup vs baseline: 3.6794x; 1.0111x over previous
//
#include <hip/hip_runtime.h>
#include <hip/hip_bf16.h>
#include <math.h>

#define SS 2048
#define EE 768
#define HH 12
#define DHH 64
#define FFF 3072
#define LL 4

typedef __hip_bfloat16 bf16;
typedef __attribute__((ext_vector_type(8))) short short8;
typedef __attribute__((ext_vector_type(4))) float f32x4;

__device__ __forceinline__ bf16 f2b(float f) { return __float2bfloat16(f); }

__device__ __forceinline__ void async_ld16(const void* g, void* l) {
  __builtin_amdgcn_global_load_lds(
      (const __attribute__((address_space(1))) void*)g,
      (__attribute__((address_space(3))) void*)l, 16, 0, 0);
}

// ---------------------------------------------------------------------------
// Fused LN: v = (readx ? x : 0) + bias + sum(parts) + extra; optionally write
// back to x; out = LN(v). parts strided by S*E; extra is a single S*E slab.
// ---------------------------------------------------------------------------
template <typename OutT>
__global__ __launch_bounds__(256) void ln_fused_kernel(
    float* x, const float* __restrict__ bias, const float* __restrict__ part,
    int nparts, const float* __restrict__ extra,
    const float* __restrict__ g, const float* __restrict__ bta,
    int writeback, int readx, OutT* __restrict__ out) {
  int row = blockIdx.x;
  int tid = threadIdx.x;
  float* xr = x + (size_t)row * EE;
  float v0 = 0.f, v1 = 0.f, v2 = 0.f;
  if (readx) { v0 = xr[tid]; v1 = xr[tid + 256]; v2 = xr[tid + 512]; }
  if (bias) { v0 += bias[tid]; v1 += bias[tid + 256]; v2 += bias[tid + 512]; }
  for (int p = 0; p < nparts; p++) {
    const float* pr = part + (size_t)p * SS * EE + (size_t)row * EE;
    v0 += pr[tid]; v1 += pr[tid + 256]; v2 += pr[tid + 512];
  }
  if (extra) {
    const float* er = extra + (size_t)row * EE;
    v0 += er[tid]; v1 += er[tid + 256]; v2 += er[tid + 512];
  }
  if (writeback) { xr[tid] = v0; xr[tid + 256] = v1; xr[tid + 512] = v2; }
  float s  = v0 + v1 + v2;
  float s2 = v0 * v0 + v1 * v1 + v2 * v2;
  #pragma unroll
  for (int off = 32; off >= 1; off >>= 1) {
    s  += __shfl_down(s,  off);
    s2 += __shfl_down(s2, off);
  }
  __shared__ float red[8];
  __shared__ float mb[2];
  int lane = tid & 63, wid = tid >> 6;
  if (lane == 0) { red[wid] = s; red[4 + wid] = s2; }
  __syncthreads();
  if (tid == 0) {
    float ts  = red[0] + red[1] + red[2] + red[3];
    float ts2 = red[4] + red[5] + red[6] + red[7];
    float mu  = ts * (1.0f / EE);
    float var = ts2 * (1.0f / EE) - mu * mu;
    mb[0] = mu; mb[1] = rsqrtf(var + 1e-5f);
  }
  __syncthreads();
  float mu = mb[0], rs = mb[1];
  OutT* orow = out + (size_t)row * EE;
  float o0 = (v0 - mu) * rs * g[tid]       + bta[tid];
  float o1 = (v1 - mu) * rs * g[tid + 256] + bta[tid + 256];
  float o2 = (v2 - mu) * rs * g[tid + 512] + bta[tid + 512];
  if constexpr (sizeof(OutT) == 4) {
    orow[tid] = o0; orow[tid + 256] = o1; orow[tid + 512] = o2;
  } else {
    orow[tid] = f2b(o0); orow[tid + 256] = f2b(o1); orow[tid + 512] = f2b(o2);
  }
}

// ---------------------------------------------------------------------------
// Vectorized mega-transpose: all weights, all layers. 64x64 tiles,
// float4 loads + short8 stores. Per-layer short offsets: Wqkv_t@0,
// Wo_t@1769472, W1_t@2359296, W2_t@4718592; layer stride 7077888.
// ---------------------------------------------------------------------------
__global__ __launch_bounds__(256) void transpose_all_kernel(
    const float* __restrict__ Wq, const float* __restrict__ Wk,
    const float* __restrict__ Wv, const float* __restrict__ Wo,
    const float* __restrict__ W1, const float* __restrict__ W2,
    bf16* __restrict__ WtAll) {
  __shared__ float tile[64][65];
  int bid = blockIdx.x;
  int l = bid / 1728, r = bid % 1728;
  bf16* base = WtAll + (size_t)l * 7077888;
  const float* src; bf16* dst; int K, N, rr;
  if (r < 432) {
    int m = r / 144; rr = r % 144;
    src = (m == 0 ? Wq : m == 1 ? Wk : Wv) + (size_t)l * EE * EE;
    dst = base + (size_t)m * 589824; K = 768; N = 768;
  } else if (r < 576) {
    rr = r - 432; src = Wo + (size_t)l * EE * EE; dst = base + 1769472; K = 768; N = 768;
  } else if (r < 1152) {
    rr = r - 576; src = W1 + (size_t)l * EE * FFF; dst = base + 2359296; K = 768; N = 3072;
  } else {
    rr = r - 1152; src = W2 + (size_t)l * FFF * EE; dst = base + 4718592; K = 3072; N = 768;
  }
  int ntn = N >> 6;
  int n0 = (rr % ntn) * 64, k0 = (rr / ntn) * 64;
  int t = threadIdx.x;
  int lr = t >> 4, lc = (t & 15) * 4;
  #pragma unroll
  for (int it = 0; it < 4; it++) {
    float4 v = *(const float4*)(src + (size_t)(k0 + lr + 16 * it) * N + n0 + lc);
    tile[lr + 16 * it][lc] = v.x; tile[lr + 16 * it][lc + 1] = v.y;
    tile[lr + 16 * it][lc + 2] = v.z; tile[lr + 16 * it][lc + 3] = v.w;
  }
  __syncthreads();
  int n = t >> 2, kc = (t & 3) * 16;
  __align__(16) bf16 tmp[16];
  #pragma unroll
  for (int j = 0; j < 16; j++) tmp[j] = f2b(tile[kc + j][n]);
  short* d = (short*)dst + (size_t)(n0 + n) * K + k0 + kc;
  *(short8*)d = *(short8*)&tmp[0];
  *(short8*)(d + 8) = *(short8*)&tmp[8];
}

// all 4 layers' q,k,v biases -> bqkv_all[l][2304]. grid 36.
__global__ __launch_bounds__(256) void concat_bias_all_kernel(
    const float* __restrict__ bq, const float* __restrict__ bk,
    const float* __restrict__ bv, float* __restrict__ out) {
  int g = blockIdx.x * 256 + threadIdx.x;
  int l = g / 2304, i = g % 2304;
  out[g] = (i < 768) ? bq[l * 768 + i]
         : (i < 1536 ? bk[l * 768 + i - 768] : bv[l * 768 + i - 1536]);
}

// ---------------------------------------------------------------------------
// bf16 MFMA GEMM: C = A[M,K](lda) @ Bt[N,K]^T (+bias). 128x128 tile, BK=64,
// XOR-swizzled k-chunks. Modes:
//  0: bias->bf16 (ld N)      1: bias+GELU->bf16 (ld N)
//  3: split-K fp32 partial   4: QKV special: n<768 -> Cv bf16 ld 768,
//     n>=768 -> transposed short4 into Cv2 = kvT[(n-768)][2048]
// ---------------------------------------------------------------------------
__global__ __launch_bounds__(256) void gemm_bf16_kernel(
    const bf16* __restrict__ A, int lda, const bf16* __restrict__ Bt,
    const float* __restrict__ bias, void* __restrict__ Cv, void* __restrict__ Cv2,
    int K, int N, int mode, int Ksplit) {
  __shared__ __align__(16) short As[128 * 64];
  __shared__ __align__(16) short Bs[128 * 64];
  const int t = threadIdx.x;
  const int wave = t >> 6, lane = t & 63;
  const int m0 = blockIdx.y * 128, n0 = blockIdx.x * 128;
  const int z = blockIdx.z;
  const int kBeg = z * Ksplit, kEnd = kBeg + Ksplit;

  const int srow = t >> 3;
  const int sw   = (t & 7) ^ (srow & 7);
  const bf16* Ag = A  + (size_t)(m0 + srow) * lda + sw * 8;
  const bf16* Bg = Bt + (size_t)(n0 + srow) * K + sw * 8;

  const int fr = lane & 15, kq = lane >> 4;
  const int wm = (wave >> 1) * 64, wn = (wave & 1) * 64;
  f32x4 acc[4][4] = {};

  for (int k0 = kBeg; k0 < kEnd; k0 += 64) {
    #pragma unroll
    for (int c = 0; c < 4; c++) {
      async_ld16(Ag + (size_t)(32 * c) * lda + k0, As + c * 2048 + wave * 512);
      async_ld16(Bg + (size_t)(32 * c) * K + k0, Bs + c * 2048 + wave * 512);
    }
    __syncthreads();
    #pragma unroll
    for (int s = 0; s < 2; s++) {
      short8 a[4], b[4];
      #pragma unroll
      for (int i = 0; i < 4; i++) {
        int r = wm + 16 * i + fr;
        int p = (kq + 4 * s) ^ (r & 7);
        a[i] = *(const short8*)(As + r * 64 + p * 8);
      }
      #pragma unroll
      for (int j = 0; j < 4; j++) {
        int r = wn + 16 * j + fr;
        int p = (kq + 4 * s) ^ (r & 7);
        b[j] = *(const short8*)(Bs + r * 64 + p * 8);
      }
      #pragma unroll
      for (int i = 0; i < 4; i++)
        #pragma unroll
        for (int j = 0; j < 4; j++)
          acc[i][j] = __builtin_amdgcn_mfma_f32_16x16x32_bf16(a[i], b[j], acc[i][j], 0, 0, 0);
    }
    __syncthreads();
  }

  // C/D layout: col = lane&15, row = (lane>>4)*4 + reg
  #pragma unroll
  for (int i = 0; i < 4; i++) {
    #pragma unroll
    for (int j = 0; j < 4; j++) {
      const int r0 = m0 + wm + 16 * i + kq * 4;
      const int c  = n0 + wn + 16 * j + fr;
      const float bv = (mode == 3) ? 0.0f : bias[c];
      if (mode == 4) {
        if (n0 < 768) {
          #pragma unroll
          for (int ri = 0; ri < 4; ri++)
            ((bf16*)Cv)[(size_t)(r0 + ri) * 768 + c] = f2b(acc[i][j][ri] + bv);
        } else {
          short4 o;
          __align__(8) bf16 tb[4];
          #pragma unroll
          for (int ri = 0; ri < 4; ri++) tb[ri] = f2b(acc[i][j][ri] + bv);
          o = *(short4*)&tb[0];
          *(short4*)((short*)Cv2 + ((size_t)(c - 768) << 11) + r0) = o;
        }
      } else {
        #pragma unroll
        for (int ri = 0; ri < 4; ri++) {
          float val = acc[i][j][ri] + bv;
          const size_t idx = (size_t)(r0 + ri) * N + c;
          if (mode == 0) {
            ((bf16*)Cv)[idx] = f2b(val);
          } else if (mode == 1) {
            val = 0.5f * val * (1.0f + erff(val * 0.70710678118654752f));
            ((bf16*)Cv)[idx] = f2b(val);
          } else {
            ((float*)Cv)[(size_t)z * SS * N + idx] = val;
          }
        }
      }
    }
  }
}

// ---------------------------------------------------------------------------
// KtV partials via MFMA, barrier/LDS-free. grid (12 h, 8), 4 waves/block;
// wave = one 64-s chunk. part[(chunk*12+h)][d1][d2] fp32.
// ---------------------------------------------------------------------------
__global__ __launch_bounds__(256) void ktv_mfma_kernel(
    const bf16* __restrict__ kvT, float* __restrict__ part) {
  const int h = blockIdx.x;
  const int lane = threadIdx.x & 63, wave = threadIdx.x >> 6;
  const int chunk = blockIdx.y * 4 + wave;
  const int s0 = chunk * 64;
  const int fr = lane & 15, kq = lane >> 4;
  const short* kT = (const short*)kvT + (size_t)h * 64 * 2048;
  const short* vT = (const short*)kvT + (size_t)(768 + h * 64) * 2048;
  f32x4 acc[4][4] = {};
  #pragma unroll
  for (int s = 0; s < 2; s++) {
    short8 a[4], b[4];
    #pragma unroll
    for (int i = 0; i < 4; i++)
      a[i] = *(const short8*)(kT + (size_t)(16 * i + fr) * 2048 + s0 + s * 32 + kq * 8);
    #pragma unroll
    for (int j = 0; j < 4; j++)
      b[j] = *(const short8*)(vT + (size_t)(16 * j + fr) * 2048 + s0 + s * 32 + kq * 8);
    #pragma unroll
    for (int i = 0; i < 4; i++)
      #pragma unroll
      for (int j = 0; j < 4; j++)
        acc[i][j] = __builtin_amdgcn_mfma_f32_16x16x32_bf16(a[i], b[j], acc[i][j], 0, 0, 0);
  }
  float* dst = part + (size_t)(chunk * 12 + h) * 4096;
  #pragma unroll
  for (int i = 0; i < 4; i++)
    #pragma unroll
    for (int j = 0; j < 4; j++)
      #pragma unroll
      for (int ri = 0; ri < 4; ri++)
        dst[(16 * i + kq * 4 + ri) * 64 + 16 * j + fr] = acc[i][j][ri];
}

// ktv[h][d1][d2] bf16 = 0.125 * sum_c part[(c*12+h)][d1][d2]. grid 192.
__global__ __launch_bounds__(256) void ktv_reduce_kernel(
    const float* __restrict__ part, bf16* __restrict__ ktvb) {
  int g = blockIdx.x * 256 + threadIdx.x;
  int h = g >> 12, rem = g & 4095;
  float s = 0.f;
  #pragma unroll 8
  for (int c = 0; c < 32; c++) s += part[(size_t)(c * 12 + h) * 4096 + rem];
  ktvb[g] = f2b(s * 0.125f);
}

// ---------------------------------------------------------------------------
// G-build: Gt[n][h*64+d1] = (M_h @ Wo_h)[d1][n].  M_h = ktvb[h] (64x64 bf16),
// Wo_h = rows h*64..h*64+63 of Wo  (via Wo_t[n][k]).  grid (6 n-tiles, 12 h),
// 4 waves; wave w covers n-sub of 32. Barrier/LDS-free.
// ---------------------------------------------------------------------------
__global__ __launch_bounds__(256) void gbuild_kernel(
    const bf16* __restrict__ ktvb, const bf16* __restrict__ Wo_t,
    bf16* __restrict__ Gt) {
  const int nt = blockIdx.x, h = blockIdx.y;
  const int lane = threadIdx.x & 63, wave = threadIdx.x >> 6;
  const int nb = nt * 128 + wave * 32;
  const int fr = lane & 15, kq = lane >> 4;
  const short* M = (const short*)ktvb + (size_t)h * 4096;       // [d1][d2]
  const short* W = (const short*)Wo_t;                          // [n][768]
  f32x4 acc[4][2] = {};
  #pragma unroll
  for (int s = 0; s < 2; s++) {
    short8 a[4], b[2];
    #pragma unroll
    for (int i = 0; i < 4; i++)
      a[i] = *(const short8*)(M + (16 * i + fr) * 64 + s * 32 + kq * 8);
    #pragma unroll
    for (int j = 0; j < 2; j++)
      b[j] = *(const short8*)(W + (size_t)(nb + 16 * j + fr) * 768 + h * 64 + s * 32 + kq * 8);
    #pragma unroll
    for (int i = 0; i < 4; i++)
      #pragma unroll
      for (int j = 0; j < 2; j++)
        acc[i][j] = __builtin_amdgcn_mfma_f32_16x16x32_bf16(a[i], b[j], acc[i][j], 0, 0, 0);
  }
  #pragma unroll
  for (int i = 0; i < 4; i++)
    #pragma unroll
    for (int j = 0; j < 2; j++) {
      const int c = nb + 16 * j + fr;          // n
      const int d1 = 16 * i + kq * 4;          // row base
      __align__(8) bf16 tb[4];
      #pragma unroll
      for (int ri = 0; ri < 4; ri++) tb[ri] = f2b(acc[i][j][ri]);
      *(short4*)((short*)Gt + (size_t)c * 768 + h * 64 + d1) = *(short4*)&tb[0];
    }
}

// ---------------------------------------------------------------------------
extern "C" void kernel_launch(void* const* d_in, const int* in_sizes, int n_in,
                              void* d_out, int out_size, void* d_ws, size_t ws_size,
                              hipStream_t stream) {
  const float* emb  = (const float*)d_in[0];
  const float* wpe  = (const float*)d_in[1];
  const float* ln1g = (const float*)d_in[2];
  const float* ln1b = (const float*)d_in[3];
  const float* Wq   = (const float*)d_in[4];
  const float* bq   = (const float*)d_in[5];
  const float* Wk   = (const float*)d_in[6];
  const float* bk   = (const float*)d_in[7];
  const float* Wv   = (const float*)d_in[8];
  const float* bv   = (const float*)d_in[9];
  const float* Wo   = (const float*)d_in[10];
  const float* bo   = (const float*)d_in[11];
  const float* ln2g = (const float*)d_in[12];
  const float* ln2b = (const float*)d_in[13];
  const float* W1   = (const float*)d_in[14];
  const float* b1   = (const float*)d_in[15];
  const float* W2   = (const float*)d_in[16];
  const float* b2   = (const float*)d_in[17];
  const float* lnfg = (const float*)d_in[18];
  const float* lnfb = (const float*)d_in[19];

  // Workspace (~115 MB of 256 MiB)
  char* w = (char*)d_ws;
  bf16*  WtAll = (bf16*)w;   w += (size_t)4 * 7077888 * 2;    // 56.6 MB
  float* bqkvA = (float*)w;  w += (size_t)4 * 2304 * 4;
  float* x     = (float*)w;  w += (size_t)SS * EE * 4;        // 6.3 MB
  bf16*  hb    = (bf16*)w;   w += (size_t)SS * EE * 2;        // 3.1 MB
  bf16*  qkvQ  = (bf16*)w;   w += (size_t)SS * EE * 2;        // 3.1 MB
  bf16*  kvT   = (bf16*)w;   w += (size_t)1536 * 2048 * 2;    // 6.3 MB
  float* part  = (float*)w;  w += (size_t)32 * 12 * 4096 * 4; // 6.3 MB
  bf16*  ktvb  = (bf16*)w;   w += (size_t)HH * 4096 * 2;      // 0.1 MB
  bf16*  Gt    = (bf16*)w;   w += (size_t)EE * EE * 2;        // 1.2 MB
  bf16*  mb2   = (bf16*)w;   w += (size_t)SS * FFF * 2;       // 12.6 MB
  float* cpart = (float*)w;  w += (size_t)3 * SS * EE * 4;    // 18.9 MB

  dim3 blk(256);
  transpose_all_kernel<<<6912, blk, 0, stream>>>(Wq, Wk, Wv, Wo, W1, W2, WtAll);
  concat_bias_all_kernel<<<36, blk, 0, stream>>>(bq, bk, bv, bqkvA);

  for (int l = 0; l < LL; l++) {
    bf16* Wl = WtAll + (size_t)l * 7077888;
    bf16* Wqkv_t = Wl;
    bf16* Wo_t   = Wl + 1769472;
    bf16* W1_t   = Wl + 2359296;
    bf16* W2_t   = Wl + 4718592;

    if (l == 0) {
      // x = emb + wpe (via parts), LN -> hb
      ln_fused_kernel<bf16><<<SS, blk, 0, stream>>>(
          x, nullptr, emb, 1, wpe, ln1g, ln1b, 1, 0, hb);
    } else {
      ln_fused_kernel<bf16><<<SS, blk, 0, stream>>>(
          x, b2 + (l - 1) * EE, cpart, 3, nullptr,
          ln1g + l * EE, ln1b + l * EE, 1, 1, hb);
    }
    // fused QKV GEMM: Q -> qkvQ (ld 768), K/V -> kvT transposed
    gemm_bf16_kernel<<<dim3(18, 16, 1), blk, 0, stream>>>(
        hb, EE, Wqkv_t, bqkvA + l * 2304, qkvQ, kvT, EE, 2304, 4, EE);
    // linear attention folded through Wo:  x += Q @ (M_h @ Wo_h)
    ktv_mfma_kernel<<<dim3(HH, 8), blk, 0, stream>>>(kvT, part);
    ktv_reduce_kernel<<<192, blk, 0, stream>>>(part, ktvb);
    gbuild_kernel<<<dim3(6, HH), blk, 0, stream>>>(ktvb, Wo_t, Gt);
    gemm_bf16_kernel<<<dim3(6, 16, 3), blk, 0, stream>>>(
        qkvQ, EE, Gt, nullptr, cpart, nullptr, EE, EE, 3, 256);
    ln_fused_kernel<bf16><<<SS, blk, 0, stream>>>(
        x, bo + l * EE, cpart, 3, nullptr, ln2g + l * EE, ln2b + l * EE, 1, 1, hb);
    // FF1 + GELU
    gemm_bf16_kernel<<<dim3(24, 16, 1), blk, 0, stream>>>(
        hb, EE, W1_t, b1 + l * FFF, mb2, nullptr, EE, FFF, 1, EE);
    // FF2 split-K=3; bias+residual folded into next LN
    gemm_bf16_kernel<<<dim3(6, 16, 3), blk, 0, stream>>>(
        mb2, FFF, W2_t, nullptr, cpart, nullptr, FFF, EE, 3, 1024);
  }
  ln_fused_kernel<float><<<SS, blk, 0, stream>>>(
      x, b2 + 3 * EE, cpart, 3, nullptr, lnfg, lnfb, 0, 1, (float*)d_out);
}